// Round 11
// baseline (6212.962 us; speedup 1.0000x reference)
//
#include <hip/hip_runtime.h>
#include <cstdint>

typedef unsigned short u16;
typedef unsigned int   u32;
typedef __bf16 v8bf  __attribute__((ext_vector_type(8)));
typedef float  v4f   __attribute__((ext_vector_type(4)));
typedef u32    u32x4 __attribute__((ext_vector_type(4)));

#define T_STEPS 1024
#define G3 1536

// ws layout (bytes). Rings/flags overlap the head of xbf (dead after k_gemm;
// memset is issued after k_gemm, before k_lstm).
#define OFF_RING0  0ull         // L0 h/c ring [4 slots][4 grp][16 rows][1024 bf16] = 524,288
#define OFF_RING1  524288ull    // L1 ring, same shape = 524,288
#define OFF_FLAGS0 1048576ull   // u32 [4 grp][128]  (4 flags per producer block)
#define OFF_FLAGS1 1050624ull   // u32 [4 grp][128]
#define OFF_XBF    0ull         // x bf16 [65536,512] 67,108,864 (dead after gemm)
#define OFF_XG     67108864ull  // xg0 bf16 [65536,1536] 201,326,592
#define OFF_WII    268435456ull // Wii layer0 bf16 [1536,512] 1,572,864
#define OFF_WPACK  270008320ull // packed recurrent B-frags (2 layers) 7,340,032
#define OFF_WPK2   277348352ull // packed Wii layer1 B-frags 1,572,864
#define OFF_BIASF  278921216ull // folded gate bias f32 [2,1536] 12,288

__device__ __forceinline__ u16 f2b(float f) {
  u32 u = __builtin_bit_cast(u32, f);
  u += 0x7fffu + ((u >> 16) & 1u);
  return (u16)(u >> 16);
}
__device__ __forceinline__ float b2f(u16 h) {
  u32 u = ((u32)h) << 16;
  return __builtin_bit_cast(float, u);
}
__device__ __forceinline__ float sigm(float x) { return 1.0f / (1.0f + __expf(-x)); }

// ---------------- prep kernels ----------------

__global__ void k_cvt(const float* __restrict__ s, u16* __restrict__ d, int n4) {
  int i = blockIdx.x * blockDim.x + threadIdx.x;
  int st = gridDim.x * blockDim.x;
  for (; i < n4; i += st) {
    float4 v = reinterpret_cast<const float4*>(s)[i];
    u32 lo = (u32)f2b(v.x) | ((u32)f2b(v.y) << 16);
    u32 hi = (u32)f2b(v.z) | ((u32)f2b(v.w) << 16);
    uint2 pk; pk.x = lo; pk.y = hi;
    reinterpret_cast<uint2*>(d)[i] = pk;
  }
}

__global__ void k_fold(const float* __restrict__ a, const float* __restrict__ b,
                       const float* __restrict__ c, float* __restrict__ o, int n) {
  int i = blockIdx.x * blockDim.x + threadIdx.x;
  if (i < n) o[i] = a[i] + b[i] + c[i];
}

// Recurrent weights -> MFMA B-frag order (both layers). [l][s][112][64][8]:
// c<96: gates tau=c>>5, kk=c&31 (K=1024: k<512 Wih, k>=512 Wic); c>=96: Whh.
__global__ void k_pack(const float* __restrict__ Wih, const float* __restrict__ Wic,
                       const float* __restrict__ Whh, u16* __restrict__ wp) {
  int t = blockIdx.x * blockDim.x + threadIdx.x;
  if (t >= 2 * 32 * 112 * 64) return;
  int lane = t & 63; int rest = t >> 6;
  int c = rest % 112; rest /= 112;
  int s = rest & 31; int l = rest >> 5;
  int col16 = lane & 15, kq = lane >> 4;
  const float* src;
  if (c < 96) {
    int tau = c >> 5, kk = c & 31;
    int col = tau * 512 + s * 16 + col16;
    int k = kk * 32 + kq * 8;
    src = (k < 512) ? (Wih + ((size_t)l * G3 + col) * 512 + k)
                    : (Wic + ((size_t)l * G3 + col) * 512 + (k - 512));
  } else {
    int kk = c - 96;
    int col = s * 16 + col16;
    int k = kk * 32 + kq * 8;
    src = Whh + ((size_t)l * 512 + col) * 512 + k;
  }
  u16 o[8];
#pragma unroll
  for (int i = 0; i < 8; ++i) o[i] = f2b(src[i]);
  uint4 v;
  v.x = (u32)o[0] | ((u32)o[1] << 16);
  v.y = (u32)o[2] | ((u32)o[3] << 16);
  v.z = (u32)o[4] | ((u32)o[5] << 16);
  v.w = (u32)o[6] | ((u32)o[7] << 16);
  reinterpret_cast<uint4*>(wp)[t] = v;
}

// Wii layer-1 -> B-frag order. [s][wg(3)][kk(16)][lane(64)][8]; B[k][col]=Wii1[col][k].
__global__ void k_pack2(const float* __restrict__ Wii, u16* __restrict__ wp2) {
  int t = blockIdx.x * blockDim.x + threadIdx.x;
  if (t >= 32 * 3 * 16 * 64) return;
  int lane = t & 63;
  int kk = (t >> 6) & 15;
  int w = (t >> 10) % 3;
  int s = t / 3072;
  int col = w * 512 + s * 16 + (lane & 15);
  int k = kk * 32 + (lane >> 4) * 8;
  const float* src = Wii + ((size_t)G3 + col) * 512 + k;   // layer-1 slice
  u16 o[8];
#pragma unroll
  for (int i = 0; i < 8; ++i) o[i] = f2b(src[i]);
  uint4 v;
  v.x = (u32)o[0] | ((u32)o[1] << 16);
  v.y = (u32)o[2] | ((u32)o[3] << 16);
  v.z = (u32)o[4] | ((u32)o[5] << 16);
  v.w = (u32)o[6] | ((u32)o[7] << 16);
  reinterpret_cast<uint4*>(wp2)[t] = v;
}

// ---------------- xg0 GEMM: C[M,1536] = A[M,512] * Bt[1536,512]^T ----------------

__global__ __launch_bounds__(256) void k_gemm(const u16* __restrict__ A,
                                              const u16* __restrict__ Bt,
                                              u16* __restrict__ C) {
  __shared__ u16 As[128 * 40];
  __shared__ u16 Bs[128 * 40];
  int m0 = blockIdx.x * 128, n0 = blockIdx.y * 128;
  int tid = threadIdx.x, lane = tid & 63, w = tid >> 6, wr = w >> 1, wc = w & 1;
  int rl = lane & 15, kq = lane >> 4;
  v4f acc[4][4] = {};
  for (int k0 = 0; k0 < 512; k0 += 32) {
#pragma unroll
    for (int c = tid; c < 1024; c += 256) {
      int row = (c & 511) >> 2, q = c & 3;
      const u16* src = (c < 512) ? (A + (size_t)(m0 + row) * 512 + k0 + q * 8)
                                 : (Bt + (size_t)(n0 + row) * 512 + k0 + q * 8);
      uint4 v = *reinterpret_cast<const uint4*>(src);
      u16* dst = (c < 512) ? (As + row * 40 + q * 8) : (Bs + row * 40 + q * 8);
      *reinterpret_cast<uint4*>(dst) = v;
    }
    __syncthreads();
    v8bf a[4], b[4];
#pragma unroll
    for (int mi = 0; mi < 4; ++mi)
      a[mi] = *reinterpret_cast<const v8bf*>(As + (wr * 64 + mi * 16 + rl) * 40 + kq * 8);
#pragma unroll
    for (int ni = 0; ni < 4; ++ni)
      b[ni] = *reinterpret_cast<const v8bf*>(Bs + (wc * 64 + ni * 16 + rl) * 40 + kq * 8);
#pragma unroll
    for (int mi = 0; mi < 4; ++mi)
#pragma unroll
      for (int ni = 0; ni < 4; ++ni)
        acc[mi][ni] = __builtin_amdgcn_mfma_f32_16x16x32_bf16(a[mi], b[ni], acc[mi][ni], 0, 0, 0);
    __syncthreads();
  }
#pragma unroll
  for (int mi = 0; mi < 4; ++mi)
#pragma unroll
    for (int ni = 0; ni < 4; ++ni)
#pragma unroll
      for (int r = 0; r < 4; ++r) {
        int row = m0 + wr * 64 + mi * 16 + kq * 4 + r;
        int col = n0 + wc * 64 + ni * 16 + rl;
        C[(size_t)row * G3 + col] = f2b(acc[mi][ni][r]);
      }
}

// ---------------- persistent 2-layer pipelined recurrence ----------------
// 128 blocks x 512 threads (R8-proven compute core: split-K, 2 waves per gate).
// NEW sync: detection separated from data. Producers store RAW h/c bf16 to the
// ring, per-wave vmcnt(0), then ONE 4B flag per wave (4 single-writer flags per
// block; monotone step counter; >= check). Consumers poll 128 flags (2 dwords
// per lane, per-wave __all) -- ~2KB/round instead of 64KB -- then bulk-load the
// 32KB payload exactly once. flags1 poll deferred until after L0 MFMA (slack);
// L1 MFMA (all waves) overlaps L0 elementwise/drain/flag (waves 0-3).
// Overwrite safety: depth-4 ring + flag monotonicity (a producer at step t+3
// implies every block flagged >= t+3, hence finished reading slot t&3).

__global__ __launch_bounds__(512, 1) void k_lstm(
    const u16* __restrict__ xg, const u16* __restrict__ wp, const u16* __restrict__ wp2,
    const float* __restrict__ biasf, const float* __restrict__ bhh,
    const float* __restrict__ xin, float* __restrict__ outs,
    float* __restrict__ hn, float* __restrict__ cn,
    char* __restrict__ ring0, char* __restrict__ ring1,
    u32* __restrict__ flags0, u32* __restrict__ flags1) {
  extern __shared__ char lds[];
  u16* alds   = (u16*)lds;                 // 16 rows x 2056 u16: [h0|c0|h1|c1]+pad
  float* olds = (float*)(lds + 65792);     // [0..2047] L0 wave tiles, [2048..4095] L1
  u16* w1lds  = (u16*)(lds + 82176);       // Wii1 B-frags: [wg(3)][kk(16)][lane][8]
  int tid = threadIdx.x, lane = tid & 63, w = tid >> 6;
  int w2 = w >> 1, half = w & 1;           // gate index / K-half
  int blk = blockIdx.x, g = blk >> 5, s = blk & 31;

  int erow = (tid >> 4) & 15, ecol = tid & 15;   // elementwise ownership (tid<256)
  int bglob = g * 16 + erow, hcol = s * 16 + ecol;
  int col16 = lane & 15, kq = lane >> 4;
  bool isGate = (w2 < 3);
  float bias0 = 0.0f, bias1 = 0.0f;
  int cbase;
  if (isGate) {
    cbase = w2 * 32 + half * 16;
    if (half == 0) {
      bias0 = biasf[w2 * 512 + s * 16 + col16];
      bias1 = biasf[1536 + w2 * 512 + s * 16 + col16];
    }
  } else {
    cbase = 96 + half * 8;
    if (half == 0) {
      bias0 = bhh[s * 16 + col16];
      bias1 = bhh[512 + s * 16 + col16];
    }
  }
  int colglob = w2 * 512 + s * 16 + col16;

  // one-time: recurrent B-frags (both layers, this wave's K-half) -> registers
  const u16* w0src = wp + (size_t)s * 57344 + (size_t)cbase * 512 + lane * 8;
  const u16* w1src = wp + 1835008 + (size_t)s * 57344 + (size_t)cbase * 512 + lane * 8;
  v8bf breg0[16], breg1[16];
  if (isGate) {
#pragma unroll
    for (int kk = 0; kk < 16; ++kk) {
      breg0[kk] = *reinterpret_cast<const v8bf*>(w0src + kk * 512);
      breg1[kk] = *reinterpret_cast<const v8bf*>(w1src + kk * 512);
    }
  } else {
#pragma unroll
    for (int kk = 0; kk < 8; ++kk) {
      breg0[kk] = *reinterpret_cast<const v8bf*>(w0src + kk * 512);
      breg1[kk] = *reinterpret_cast<const v8bf*>(w1src + kk * 512);
    }
  }
  // one-time: Wii1 B-frag slice -> LDS (48KB)
  {
    const uint4* src = reinterpret_cast<const uint4*>(wp2) + (size_t)s * 3072;
    for (int i = tid; i < 3072; i += 512)
      reinterpret_cast<uint4*>(w1lds)[i] = src[i];
  }
  float c0 = 0.0f, c1 = 0.0f;
  __syncthreads();

  const u32* fb0 = flags0 + g * 128;
  const u32* fb1 = flags1 + g * 128;
  int prow = tid >> 5, pcb = (tid & 31) * 32;   // payload->LDS mapping

  auto Af = [&](int base, int kg) {
    return *reinterpret_cast<const v8bf*>(alds + col16 * 2056 + base + kg * 32 + kq * 8);
  };

  for (int t = 0; t <= T_STEPS; ++t) {
    bool doL0 = (t < T_STEPS), doL1 = (t > 0);

    // ---- prefetch L0 read-only data (plain cached loads; drained by poll) ----
    float seed0[4] = {0.f, 0.f, 0.f, 0.f};
    float xi0 = 0.0f;
    if (doL0) {
      if (half == 0) {
        if (isGate) {
          const u16* xgp = xg + (size_t)(t * 64 + g * 16 + kq * 4) * G3 + colglob;
#pragma unroll
          for (int r4 = 0; r4 < 4; ++r4) seed0[r4] = b2f(xgp[(size_t)r4 * G3]) + bias0;
        } else {
#pragma unroll
          for (int r4 = 0; r4 < 4; ++r4) seed0[r4] = bias0;
        }
      }
      if (tid < 256) xi0 = xin[(size_t)(t * 64 + bglob) * 512 + hcol];
    }

    // ---- flags0 poll (per-wave, ~0.5KB/round) ----
    {
      u32 tgt = (u32)t; u32 it = 0;
      for (;;) {
        u32 f0, f1;
        asm volatile("global_load_dword %0, %1, off sc0 sc1"
                     : "=v"(f0) : "v"(fb0 + lane) : "memory");
        asm volatile("global_load_dword %0, %1, off sc0 sc1"
                     : "=v"(f1) : "v"(fb0 + 64 + lane) : "memory");
        asm volatile("s_waitcnt vmcnt(0)" ::: "memory");
        if (__all((f0 >= tgt) && (f1 >= tgt))) break;
        if (++it > (1u << 12)) break;
        __builtin_amdgcn_s_sleep(1);
      }
      __builtin_amdgcn_sched_barrier(0);
    }
    // ---- payload0: single-shot 32KB raw load -> LDS [h0|c0] ----
    {
      const char* pb = ring0 + ((size_t)(t & 3) * 4 + g) * 32768 + (size_t)tid * 64;
      u32x4 p[4];
#pragma unroll
      for (int k = 0; k < 4; ++k)
        asm volatile("global_load_dwordx4 %0, %1, off sc0 sc1"
                     : "=v"(p[k]) : "v"(pb + k * 16) : "memory");
      asm volatile("s_waitcnt vmcnt(0)" ::: "memory");
      __builtin_amdgcn_sched_barrier(0);
#pragma unroll
      for (int k = 0; k < 4; ++k)
        *reinterpret_cast<u32x4*>(alds + prow * 2056 + pcb + k * 8) = p[k];
    }
    __syncthreads();   // S1: h0/c0 staged

    // =========================== LAYER 0 MFMA: position t ===========================
    if (doL0) {
      v4f ac0, ac1, ac2, ac3;
#pragma unroll
      for (int r4 = 0; r4 < 4; ++r4) { ac0[r4] = seed0[r4]; ac1[r4] = 0.f; ac2[r4] = 0.f; ac3[r4] = 0.f; }
      if (isGate) {
#pragma unroll
        for (int kk = 0; kk < 16; kk += 4) {
          int kg = half * 16 + kk;
          ac0 = __builtin_amdgcn_mfma_f32_16x16x32_bf16(Af(0, kg + 0), breg0[kk + 0], ac0, 0, 0, 0);
          ac1 = __builtin_amdgcn_mfma_f32_16x16x32_bf16(Af(0, kg + 1), breg0[kk + 1], ac1, 0, 0, 0);
          ac2 = __builtin_amdgcn_mfma_f32_16x16x32_bf16(Af(0, kg + 2), breg0[kk + 2], ac2, 0, 0, 0);
          ac3 = __builtin_amdgcn_mfma_f32_16x16x32_bf16(Af(0, kg + 3), breg0[kk + 3], ac3, 0, 0, 0);
        }
      } else {
#pragma unroll
        for (int kk = 0; kk < 8; kk += 4) {
          int kg = half * 8 + kk;
          ac0 = __builtin_amdgcn_mfma_f32_16x16x32_bf16(Af(0, kg + 0), breg0[kk + 0], ac0, 0, 0, 0);
          ac1 = __builtin_amdgcn_mfma_f32_16x16x32_bf16(Af(0, kg + 1), breg0[kk + 1], ac1, 0, 0, 0);
          ac2 = __builtin_amdgcn_mfma_f32_16x16x32_bf16(Af(0, kg + 2), breg0[kk + 2], ac2, 0, 0, 0);
          ac3 = __builtin_amdgcn_mfma_f32_16x16x32_bf16(Af(0, kg + 3), breg0[kk + 3], ac3, 0, 0, 0);
        }
      }
      v4f acc;
#pragma unroll
      for (int r4 = 0; r4 < 4; ++r4) acc[r4] = (ac0[r4] + ac1[r4]) + (ac2[r4] + ac3[r4]);
#pragma unroll
      for (int r4 = 0; r4 < 4; ++r4) olds[w * 256 + (kq * 4 + r4) * 16 + col16] = acc[r4];
    }

    // ---- flags1 poll (deferred; producers flagged it late last iter) + payload1 ----
    if (doL1) {
      u32 tgt = (u32)(t - 1); u32 it = 0;
      for (;;) {
        u32 f0, f1;
        asm volatile("global_load_dword %0, %1, off sc0 sc1"
                     : "=v"(f0) : "v"(fb1 + lane) : "memory");
        asm volatile("global_load_dword %0, %1, off sc0 sc1"
                     : "=v"(f1) : "v"(fb1 + 64 + lane) : "memory");
        asm volatile("s_waitcnt vmcnt(0)" ::: "memory");
        if (__all((f0 >= tgt) && (f1 >= tgt))) break;
        if (++it > (1u << 12)) break;
        __builtin_amdgcn_s_sleep(1);
      }
      __builtin_amdgcn_sched_barrier(0);
      const char* pb = ring1 + ((size_t)((t - 1) & 3) * 4 + g) * 32768 + (size_t)tid * 64;
      u32x4 p[4];
#pragma unroll
      for (int k = 0; k < 4; ++k)
        asm volatile("global_load_dwordx4 %0, %1, off sc0 sc1"
                     : "=v"(p[k]) : "v"(pb + k * 16) : "memory");
      asm volatile("s_waitcnt vmcnt(0)" ::: "memory");
      __builtin_amdgcn_sched_barrier(0);
#pragma unroll
      for (int k = 0; k < 4; ++k)
        *reinterpret_cast<u32x4*>(alds + prow * 2056 + 1024 + pcb + k * 8) = p[k];
    }
    __syncthreads();   // S2: L0 olds + h1/c1 staged

    // ---- L0 elementwise + ring0 store + flag (waves 0-3) ----
    if (doL0 && tid < 256) {
      float gi = olds[tid] + olds[256 + tid];
      float gf = olds[512 + tid] + olds[768 + tid];
      float go = olds[1024 + tid] + olds[1280 + tid];
      float gg = olds[1536 + tid] + olds[1792 + tid];
      float i_s = sigm(gi), f_s = sigm(gf), o_s = sigm(go);
      float cg = tanhf(gg);
      float cy = f_s * c0 + i_s * cg;
      float hy = o_s * (tanhf(cy) + xi0);
      c0 = cy;
      u16 hyb = f2b(hy), cyb = f2b(cy);
      char* rb = ring0 + ((size_t)((t + 1) & 3) * 4 + g) * 32768;
      void* ph = rb + (size_t)(erow * 1024 + hcol) * 2;
      void* pc = rb + (size_t)(erow * 1024 + 512 + hcol) * 2;
      asm volatile("global_store_short %0, %1, off sc0 sc1" :: "v"(ph), "v"((u32)hyb) : "memory");
      asm volatile("global_store_short %0, %1, off sc0 sc1" :: "v"(pc), "v"((u32)cyb) : "memory");
      asm volatile("s_waitcnt vmcnt(0)" ::: "memory");
      if (lane == 0) {
        u32* fp = flags0 + g * 128 + s * 4 + w;
        u32 fv = (u32)(t + 1);
        asm volatile("global_store_dword %0, %1, off sc0 sc1" :: "v"(fp), "v"(fv) : "memory");
      }
      if (t == T_STEPS - 1) {
        hn[bglob * 512 + hcol] = hy;
        cn[bglob * 512 + hcol] = cy;
      }
    }

    // ========================= LAYER 1 MFMA: position t-1 (all waves; overlaps
    // waves 0-3's L0 elementwise via wave scheduling) =========================
    if (doL1) {
      v4f ac0, ac1, ac2, ac3;
#pragma unroll
      for (int r4 = 0; r4 < 4; ++r4) { ac0[r4] = bias1; ac1[r4] = 0.f; ac2[r4] = 0.f; ac3[r4] = 0.f; }
      if (isGate) {
#pragma unroll
        for (int kk = 0; kk < 16; kk += 4) {   // h1|c1 recurrent, this K-half
          int kg = half * 16 + kk;
          ac0 = __builtin_amdgcn_mfma_f32_16x16x32_bf16(Af(1024, kg + 0), breg1[kk + 0], ac0, 0, 0, 0);
          ac1 = __builtin_amdgcn_mfma_f32_16x16x32_bf16(Af(1024, kg + 1), breg1[kk + 1], ac1, 0, 0, 0);
          ac2 = __builtin_amdgcn_mfma_f32_16x16x32_bf16(Af(1024, kg + 2), breg1[kk + 2], ac2, 0, 0, 0);
          ac3 = __builtin_amdgcn_mfma_f32_16x16x32_bf16(Af(1024, kg + 3), breg1[kk + 3], ac3, 0, 0, 0);
        }
#pragma unroll
        for (int kx = 0; kx < 8; kx += 4) {    // x1 @ Wii1, this K-half (8 of 16)
          int kg = half * 8 + kx;
          ac0 = __builtin_amdgcn_mfma_f32_16x16x32_bf16(Af(0, kg + 0),
                  *reinterpret_cast<const v8bf*>(w1lds + ((w2 * 16 + kg + 0) * 64 + lane) * 8), ac0, 0, 0, 0);
          ac1 = __builtin_amdgcn_mfma_f32_16x16x32_bf16(Af(0, kg + 1),
                  *reinterpret_cast<const v8bf*>(w1lds + ((w2 * 16 + kg + 1) * 64 + lane) * 8), ac1, 0, 0, 0);
          ac2 = __builtin_amdgcn_mfma_f32_16x16x32_bf16(Af(0, kg + 2),
                  *reinterpret_cast<const v8bf*>(w1lds + ((w2 * 16 + kg + 2) * 64 + lane) * 8), ac2, 0, 0, 0);
          ac3 = __builtin_amdgcn_mfma_f32_16x16x32_bf16(Af(0, kg + 3),
                  *reinterpret_cast<const v8bf*>(w1lds + ((w2 * 16 + kg + 3) * 64 + lane) * 8), ac3, 0, 0, 0);
        }
      } else {
#pragma unroll
        for (int kk = 0; kk < 8; kk += 4) {    // cell: h1 only, this K-half
          int kg = half * 8 + kk;
          ac0 = __builtin_amdgcn_mfma_f32_16x16x32_bf16(Af(1024, kg + 0), breg1[kk + 0], ac0, 0, 0, 0);
          ac1 = __builtin_amdgcn_mfma_f32_16x16x32_bf16(Af(1024, kg + 1), breg1[kk + 1], ac1, 0, 0, 0);
          ac2 = __builtin_amdgcn_mfma_f32_16x16x32_bf16(Af(1024, kg + 2), breg1[kk + 2], ac2, 0, 0, 0);
          ac3 = __builtin_amdgcn_mfma_f32_16x16x32_bf16(Af(1024, kg + 3), breg1[kk + 3], ac3, 0, 0, 0);
        }
      }
      v4f acc;
#pragma unroll
      for (int r4 = 0; r4 < 4; ++r4) acc[r4] = (ac0[r4] + ac1[r4]) + (ac2[r4] + ac3[r4]);
#pragma unroll
      for (int r4 = 0; r4 < 4; ++r4) olds[2048 + w * 256 + (kq * 4 + r4) * 16 + col16] = acc[r4];
    }
    __syncthreads();   // S3: L1 olds ready

    // ---- L1 elementwise + ring1 store + flag + outs (waves 0-3) ----
    if (doL1 && tid < 256) {
      float xi1 = b2f(alds[erow * 2056 + hcol]);   // h0 = L0 out pos t-1 (stable to S4)
      float gi = olds[2048 + tid] + olds[2304 + tid];
      float gf = olds[2560 + tid] + olds[2816 + tid];
      float go = olds[3072 + tid] + olds[3328 + tid];
      float gg = olds[3584 + tid] + olds[3840 + tid];
      float i_s = sigm(gi), f_s = sigm(gf), o_s = sigm(go);
      float cg = tanhf(gg);
      float cy = f_s * c1 + i_s * cg;
      float hy = o_s * (tanhf(cy) + xi1);
      c1 = cy;
      u16 hyb = f2b(hy), cyb = f2b(cy);
      char* rb = ring1 + ((size_t)(t & 3) * 4 + g) * 32768;
      void* ph = rb + (size_t)(erow * 1024 + hcol) * 2;
      void* pc = rb + (size_t)(erow * 1024 + 512 + hcol) * 2;
      asm volatile("global_store_short %0, %1, off sc0 sc1" :: "v"(ph), "v"((u32)hyb) : "memory");
      asm volatile("global_store_short %0, %1, off sc0 sc1" :: "v"(pc), "v"((u32)cyb) : "memory");
      asm volatile("s_waitcnt vmcnt(0)" ::: "memory");
      if (lane == 0) {
        u32* fp = flags1 + g * 128 + s * 4 + w;
        u32 fv = (u32)t;
        asm volatile("global_store_dword %0, %1, off sc0 sc1" :: "v"(fp), "v"(fv) : "memory");
      }
      outs[(size_t)((t - 1) * 64 + bglob) * 512 + hcol] = hy;
      if (t == T_STEPS) {
        hn[32768 + bglob * 512 + hcol] = hy;
        cn[32768 + bglob * 512 + hcol] = cy;
      }
    }
    __syncthreads();   // S4: all alds/olds reads done before next iter's writes
  }
}

// ---------------- launch ----------------

extern "C" void kernel_launch(void* const* d_in, const int* in_sizes, int n_in,
                              void* d_out, int out_size, void* d_ws, size_t ws_size,
                              hipStream_t stream) {
  const float* x   = (const float*)d_in[0];
  const float* Wii = (const float*)d_in[1];
  const float* Wic = (const float*)d_in[2];
  const float* Wih = (const float*)d_in[3];
  const float* bii = (const float*)d_in[4];
  const float* bic = (const float*)d_in[5];
  const float* bih = (const float*)d_in[6];
  const float* Whh = (const float*)d_in[7];
  const float* bhh = (const float*)d_in[8];
  float* out = (float*)d_out;
  char* ws = (char*)d_ws;

  u16* xbf     = (u16*)(ws + OFF_XBF);
  u16* xgb     = (u16*)(ws + OFF_XG);
  u16* wiib    = (u16*)(ws + OFF_WII);
  u16* wpack   = (u16*)(ws + OFF_WPACK);
  u16* wpk2    = (u16*)(ws + OFF_WPK2);
  float* biasf = (float*)(ws + OFF_BIASF);

  hipFuncSetAttribute(reinterpret_cast<const void*>(k_lstm),
                      hipFuncAttributeMaxDynamicSharedMemorySize, 131328);

  // prep
  k_cvt <<<2048, 256, 0, stream>>>(x, xbf, 8388608);
  k_cvt <<<768, 256, 0, stream>>>(Wii, wiib, 196608);          // layer-0 Wii only
  k_fold<<<12, 256, 0, stream>>>(bii, bic, bih, biasf, 3072);
  k_pack<<<1792, 256, 0, stream>>>(Wih, Wic, Whh, wpack);
  k_pack2<<<384, 256, 0, stream>>>(Wii, wpk2);
  k_gemm<<<dim3(512, 12), 256, 0, stream>>>(xbf, wiib, xgb);   // xg0 only

  // rings + flags overlap head of xbf: clear AFTER k_gemm consumed it.
  hipMemsetAsync(ws + OFF_RING0, 0, 1052672, stream);

  float* hn = out + 33554432;
  float* cn = out + 33554432 + 65536;
  k_lstm<<<128, 512, 131328, stream>>>(
      xgb, wpack, wpk2, biasf, bhh, x, out, hn, cn,
      ws + OFF_RING0, ws + OFF_RING1,
      (u32*)(ws + OFF_FLAGS0), (u32*)(ws + OFF_FLAGS1));
}

// Round 13
// 5314.643 us; speedup vs baseline: 1.1690x; 1.1690x over previous
//
#include <hip/hip_runtime.h>
#include <cstdint>

typedef unsigned short u16;
typedef unsigned int   u32;
typedef __bf16 v8bf  __attribute__((ext_vector_type(8)));
typedef float  v4f   __attribute__((ext_vector_type(4)));
typedef u32    u32x2 __attribute__((ext_vector_type(2)));
typedef u32    u32x4 __attribute__((ext_vector_type(4)));

#define T_STEPS 1024
#define G3 1536

// ws layout (bytes). Rings overlap the head of xbf (dead after k_gemm; memset
// is issued after k_gemm, before k_lstm).
#define OFF_RING0 0ull          // L0 h/c ring [4 slots][4 grp][16 rows][512] 8B = 1,048,576
#define OFF_RING1 1048576ull    // L1 h/c ring, same shape = 1,048,576
#define OFF_XBF   0ull          // x bf16 [65536,512] 67,108,864 (dead after gemm)
#define OFF_XG    67108864ull   // xg0 bf16 [65536,1536] 201,326,592
#define OFF_WII   268435456ull  // Wii layer0 bf16 [1536,512] 1,572,864
#define OFF_WPACK 270008320ull  // packed recurrent B-frags (2 layers) 7,340,032
#define OFF_WPK2  277348352ull  // packed Wii layer1 B-frags 1,572,864
#define OFF_BIASF 278921216ull  // folded gate bias f32 [2,1536] 12,288

__device__ __forceinline__ u16 f2b(float f) {
  u32 u = __builtin_bit_cast(u32, f);
  u += 0x7fffu + ((u >> 16) & 1u);
  return (u16)(u >> 16);
}
__device__ __forceinline__ float b2f(u16 h) {
  u32 u = ((u32)h) << 16;
  return __builtin_bit_cast(float, u);
}
__device__ __forceinline__ float sigm(float x) { return 1.0f / (1.0f + __expf(-x)); }

// LDS-only barrier: does NOT drain vmem (global stores/loads stay in flight).
// Safe here: all cross-wave LDS communication is lgkm-fenced; global-data
// visibility is handled by the explicit ring polls, never by barriers.
__device__ __forceinline__ void bar_lds() {
  asm volatile("s_waitcnt lgkmcnt(0)\n\ts_barrier" ::: "memory");
}

// ---------------- prep kernels ----------------

__global__ void k_cvt(const float* __restrict__ s, u16* __restrict__ d, int n4) {
  int i = blockIdx.x * blockDim.x + threadIdx.x;
  int st = gridDim.x * blockDim.x;
  for (; i < n4; i += st) {
    float4 v = reinterpret_cast<const float4*>(s)[i];
    u32 lo = (u32)f2b(v.x) | ((u32)f2b(v.y) << 16);
    u32 hi = (u32)f2b(v.z) | ((u32)f2b(v.w) << 16);
    uint2 pk; pk.x = lo; pk.y = hi;
    reinterpret_cast<uint2*>(d)[i] = pk;
  }
}

__global__ void k_fold(const float* __restrict__ a, const float* __restrict__ b,
                       const float* __restrict__ c, float* __restrict__ o, int n) {
  int i = blockIdx.x * blockDim.x + threadIdx.x;
  if (i < n) o[i] = a[i] + b[i] + c[i];
}

// Recurrent weights -> MFMA B-frag order (both layers). [l][s][112][64][8]:
// c<96: gates tau=c>>5, kk=c&31 (K=1024: k<512 Wih, k>=512 Wic); c>=96: Whh.
__global__ void k_pack(const float* __restrict__ Wih, const float* __restrict__ Wic,
                       const float* __restrict__ Whh, u16* __restrict__ wp) {
  int t = blockIdx.x * blockDim.x + threadIdx.x;
  if (t >= 2 * 32 * 112 * 64) return;
  int lane = t & 63; int rest = t >> 6;
  int c = rest % 112; rest /= 112;
  int s = rest & 31; int l = rest >> 5;
  int col16 = lane & 15, kq = lane >> 4;
  const float* src;
  if (c < 96) {
    int tau = c >> 5, kk = c & 31;
    int col = tau * 512 + s * 16 + col16;
    int k = kk * 32 + kq * 8;
    src = (k < 512) ? (Wih + ((size_t)l * G3 + col) * 512 + k)
                    : (Wic + ((size_t)l * G3 + col) * 512 + (k - 512));
  } else {
    int kk = c - 96;
    int col = s * 16 + col16;
    int k = kk * 32 + kq * 8;
    src = Whh + ((size_t)l * 512 + col) * 512 + k;
  }
  u16 o[8];
#pragma unroll
  for (int i = 0; i < 8; ++i) o[i] = f2b(src[i]);
  uint4 v;
  v.x = (u32)o[0] | ((u32)o[1] << 16);
  v.y = (u32)o[2] | ((u32)o[3] << 16);
  v.z = (u32)o[4] | ((u32)o[5] << 16);
  v.w = (u32)o[6] | ((u32)o[7] << 16);
  reinterpret_cast<uint4*>(wp)[t] = v;
}

// Wii layer-1 -> B-frag order. [s][w2(3)][kk(16)][lane(64)][8]; B[k][col]=Wii1[col][k].
__global__ void k_pack2(const float* __restrict__ Wii, u16* __restrict__ wp2) {
  int t = blockIdx.x * blockDim.x + threadIdx.x;
  if (t >= 32 * 3 * 16 * 64) return;
  int lane = t & 63;
  int kk = (t >> 6) & 15;
  int w = (t >> 10) % 3;
  int s = t / 3072;
  int col = w * 512 + s * 16 + (lane & 15);
  int k = kk * 32 + (lane >> 4) * 8;
  const float* src = Wii + ((size_t)G3 + col) * 512 + k;   // layer-1 slice
  u16 o[8];
#pragma unroll
  for (int i = 0; i < 8; ++i) o[i] = f2b(src[i]);
  uint4 v;
  v.x = (u32)o[0] | ((u32)o[1] << 16);
  v.y = (u32)o[2] | ((u32)o[3] << 16);
  v.z = (u32)o[4] | ((u32)o[5] << 16);
  v.w = (u32)o[6] | ((u32)o[7] << 16);
  reinterpret_cast<uint4*>(wp2)[t] = v;
}

// ---------------- xg0 GEMM: C[M,1536] = A[M,512] * Bt[1536,512]^T ----------------

__global__ __launch_bounds__(256) void k_gemm(const u16* __restrict__ A,
                                              const u16* __restrict__ Bt,
                                              u16* __restrict__ C) {
  __shared__ u16 As[128 * 40];
  __shared__ u16 Bs[128 * 40];
  int m0 = blockIdx.x * 128, n0 = blockIdx.y * 128;
  int tid = threadIdx.x, lane = tid & 63, w = tid >> 6, wr = w >> 1, wc = w & 1;
  int rl = lane & 15, kq = lane >> 4;
  v4f acc[4][4] = {};
  for (int k0 = 0; k0 < 512; k0 += 32) {
#pragma unroll
    for (int c = tid; c < 1024; c += 256) {
      int row = (c & 511) >> 2, q = c & 3;
      const u16* src = (c < 512) ? (A + (size_t)(m0 + row) * 512 + k0 + q * 8)
                                 : (Bt + (size_t)(n0 + row) * 512 + k0 + q * 8);
      uint4 v = *reinterpret_cast<const uint4*>(src);
      u16* dst = (c < 512) ? (As + row * 40 + q * 8) : (Bs + row * 40 + q * 8);
      *reinterpret_cast<uint4*>(dst) = v;
    }
    __syncthreads();
    v8bf a[4], b[4];
#pragma unroll
    for (int mi = 0; mi < 4; ++mi)
      a[mi] = *reinterpret_cast<const v8bf*>(As + (wr * 64 + mi * 16 + rl) * 40 + kq * 8);
#pragma unroll
    for (int ni = 0; ni < 4; ++ni)
      b[ni] = *reinterpret_cast<const v8bf*>(Bs + (wc * 64 + ni * 16 + rl) * 40 + kq * 8);
#pragma unroll
    for (int mi = 0; mi < 4; ++mi)
#pragma unroll
      for (int ni = 0; ni < 4; ++ni)
        acc[mi][ni] = __builtin_amdgcn_mfma_f32_16x16x32_bf16(a[mi], b[ni], acc[mi][ni], 0, 0, 0);
    __syncthreads();
  }
#pragma unroll
  for (int mi = 0; mi < 4; ++mi)
#pragma unroll
    for (int ni = 0; ni < 4; ++ni)
#pragma unroll
      for (int r = 0; r < 4; ++r) {
        int row = m0 + wr * 64 + mi * 16 + kq * 4 + r;
        int col = n0 + wc * 64 + ni * 16 + rl;
        C[(size_t)row * G3 + col] = f2b(acc[mi][ni][r]);
      }
}

// ---------------- persistent 2-layer pipelined recurrence ----------------
// R8 skeleton (proven 5338us) + three fixes:
// (1) in-loop barriers are LDS-only (raw s_barrier + lgkmcnt) -- no implicit
//     vmcnt(0) store drains 5x/iter (hipcc adds those to __syncthreads);
// (2) ring0 loads speculatively issued at iter TAIL into persistent rA --
//     they survive the raw barrier, so the head check is drain+tag only;
// (3) xg seeds + xi prefetched one iter ahead (plain loads at tail).
// Retry rounds reload ALL 8 chunks (no divergent "=v" preserve hazard).
// Protocol bytes/tags identical to R8: tagged 8B packets {h|c<<16, tag},
// sc0 sc1 (L3), depth-4 rings.

__global__ __launch_bounds__(512, 1) void k_lstm(
    const u16* __restrict__ xg, const u16* __restrict__ wp, const u16* __restrict__ wp2,
    const float* __restrict__ biasf, const float* __restrict__ bhh,
    const float* __restrict__ xin, float* __restrict__ outs,
    float* __restrict__ hn, float* __restrict__ cn,
    char* __restrict__ ring0, char* __restrict__ ring1) {
  extern __shared__ char lds[];
  u16* alds   = (u16*)lds;                 // 16 rows x 2056 u16: [h0|c0|h1|c1]+pad
  float* olds = (float*)(lds + 65792);     // 8 wave-tiles [16][16] f32
  u16* w1lds  = (u16*)(lds + 73984);       // Wii1 B-frags: [w2(3)][kk(16)][lane][8]
  int tid = threadIdx.x, lane = tid & 63, w = tid >> 6;
  int w2 = w >> 1, half = w & 1;           // gate index / K-half
  int blk = blockIdx.x, g = blk >> 5, s = blk & 31;

  int erow = (tid >> 4) & 15, ecol = tid & 15;   // elementwise ownership (tid<256)
  int bglob = g * 16 + erow, hcol = s * 16 + ecol;
  int col16 = lane & 15, kq = lane >> 4;
  bool isGate = (w2 < 3);
  float bias0 = 0.0f, bias1 = 0.0f;
  int cbase;
  if (isGate) {
    cbase = w2 * 32 + half * 16;
    if (half == 0) {
      bias0 = biasf[w2 * 512 + s * 16 + col16];
      bias1 = biasf[1536 + w2 * 512 + s * 16 + col16];
    }
  } else {
    cbase = 96 + half * 8;
    if (half == 0) {
      bias0 = bhh[s * 16 + col16];
      bias1 = bhh[512 + s * 16 + col16];
    }
  }
  int colglob = w2 * 512 + s * 16 + col16;

  // ---- earliest: speculative ring0 slot-0 loads (persistent regs) ----
  u32x4 rA[8];
  {
    const char* pb = ring0 + (size_t)g * 65536 + (size_t)tid * 16;
#pragma unroll
    for (int i = 0; i < 8; ++i)
      asm volatile("global_load_dwordx4 %0, %1, off sc0 sc1"
                   : "=v"(rA[i]) : "v"(pb + (size_t)i * 8192) : "memory");
  }

  // one-time: recurrent B-frags (both layers, this wave's K-half) -> registers
  const u16* w0src = wp + (size_t)s * 57344 + (size_t)cbase * 512 + lane * 8;
  const u16* w1src = wp + 1835008 + (size_t)s * 57344 + (size_t)cbase * 512 + lane * 8;
  v8bf breg0[16], breg1[16];
  if (isGate) {
#pragma unroll
    for (int kk = 0; kk < 16; ++kk) {
      breg0[kk] = *reinterpret_cast<const v8bf*>(w0src + kk * 512);
      breg1[kk] = *reinterpret_cast<const v8bf*>(w1src + kk * 512);
    }
  } else {
#pragma unroll
    for (int kk = 0; kk < 8; ++kk) {
      breg0[kk] = *reinterpret_cast<const v8bf*>(w0src + kk * 512);
      breg1[kk] = *reinterpret_cast<const v8bf*>(w1src + kk * 512);
    }
  }
  // one-time: Wii1 B-frag slice -> LDS (48KB)
  {
    const uint4* src = reinterpret_cast<const uint4*>(wp2) + (size_t)s * 3072;
    for (int i = tid; i < 3072; i += 512)
      reinterpret_cast<uint4*>(w1lds)[i] = src[i];
  }
  // one-iter-ahead prefetch state (t=0)
  float pre_s0 = 0.f, pre_s1 = 0.f, pre_s2 = 0.f, pre_s3 = 0.f, pre_xi = 0.f;
  if (isGate && half == 0) {
    const u16* xgp = xg + (size_t)(g * 16 + kq * 4) * G3 + colglob;
    pre_s0 = b2f(xgp[0]);
    pre_s1 = b2f(xgp[(size_t)G3]);
    pre_s2 = b2f(xgp[(size_t)2 * G3]);
    pre_s3 = b2f(xgp[(size_t)3 * G3]);
  }
  if (tid < 256) pre_xi = xin[(size_t)bglob * 512 + hcol];
  float c0 = 0.0f, c1 = 0.0f;
  __syncthreads();   // prologue: full barrier once (drains everything incl. rA; fine)

  auto Af = [&](int base, int kg) {
    return *reinterpret_cast<const v8bf*>(alds + col16 * 2056 + base + kg * 32 + kq * 8);
  };

  for (int t = 0; t <= T_STEPS; ++t) {
    bool doL0 = (t < T_STEPS), doL1 = (t > 0);

    // ---- seeds from prefetched values (no memory on critical path) ----
    float seed0[4] = {0.f, 0.f, 0.f, 0.f};
    float xi0 = 0.0f;
    if (doL0) {
      if (half == 0) {
        if (isGate) {
          seed0[0] = pre_s0 + bias0; seed0[1] = pre_s1 + bias0;
          seed0[2] = pre_s2 + bias0; seed0[3] = pre_s3 + bias0;
        } else {
#pragma unroll
          for (int r4 = 0; r4 < 4; ++r4) seed0[r4] = bias0;
        }
      }
      if (tid < 256) xi0 = pre_xi;
    }

    // ---- ring0 check: drain spec loads, tag-check, full-reload retry ----
    {
      const char* pb = ring0 + ((size_t)(t & 3) * 4 + g) * 65536 + (size_t)tid * 16;
      u32 exp = (u32)t, it = 0;
      asm volatile("s_waitcnt vmcnt(0)" ::: "memory");
      __builtin_amdgcn_sched_barrier(0);
      for (;;) {
        bool ok = true;
#pragma unroll
        for (int i = 0; i < 8; ++i) ok = ok && (rA[i][1] == exp) && (rA[i][3] == exp);
        if (ok) break;
        if (++it > (1u << 11)) break;
        __builtin_amdgcn_s_sleep(1);
#pragma unroll
        for (int i = 0; i < 8; ++i)
          asm volatile("global_load_dwordx4 %0, %1, off sc0 sc1"
                       : "=v"(rA[i]) : "v"(pb + (size_t)i * 8192) : "memory");
        asm volatile("s_waitcnt vmcnt(0)" ::: "memory");
        __builtin_amdgcn_sched_barrier(0);
      }
      __builtin_amdgcn_sched_barrier(0);
#pragma unroll
      for (int i = 0; i < 8; ++i) {
        int p = tid + i * 512;
        int row = p >> 8, c2 = p & 255;
        u32 hw = (rA[i][0] & 0xffffu) | (rA[i][2] << 16);
        u32 cw = (rA[i][0] >> 16) | (rA[i][2] & 0xffff0000u);
        *reinterpret_cast<u32*>(alds + row * 2056 + 2 * c2) = hw;
        *reinterpret_cast<u32*>(alds + row * 2056 + 512 + 2 * c2) = cw;
      }
    }

    // ---- issue ring1 loads EARLY (checked after L0; latency hidden) ----
    u32x4 r2[8];
    if (doL1) {
      const char* pb = ring1 + ((size_t)((t - 1) & 3) * 4 + g) * 65536 + (size_t)tid * 16;
#pragma unroll
      for (int i = 0; i < 8; ++i)
        asm volatile("global_load_dwordx4 %0, %1, off sc0 sc1"
                     : "=v"(r2[i]) : "v"(pb + (size_t)i * 8192) : "memory");
    }
    bar_lds();   // S1: ring0 staged (LDS-only barrier; r2 stays in flight)

    // =========================== LAYER 0: position t ===========================
    if (doL0) {
      v4f ac0, ac1, ac2, ac3;
#pragma unroll
      for (int r4 = 0; r4 < 4; ++r4) { ac0[r4] = seed0[r4]; ac1[r4] = 0.f; ac2[r4] = 0.f; ac3[r4] = 0.f; }
      if (isGate) {
#pragma unroll
        for (int kk = 0; kk < 16; kk += 4) {
          int kg = half * 16 + kk;
          ac0 = __builtin_amdgcn_mfma_f32_16x16x32_bf16(Af(0, kg + 0), breg0[kk + 0], ac0, 0, 0, 0);
          ac1 = __builtin_amdgcn_mfma_f32_16x16x32_bf16(Af(0, kg + 1), breg0[kk + 1], ac1, 0, 0, 0);
          ac2 = __builtin_amdgcn_mfma_f32_16x16x32_bf16(Af(0, kg + 2), breg0[kk + 2], ac2, 0, 0, 0);
          ac3 = __builtin_amdgcn_mfma_f32_16x16x32_bf16(Af(0, kg + 3), breg0[kk + 3], ac3, 0, 0, 0);
        }
      } else {
#pragma unroll
        for (int kk = 0; kk < 8; kk += 4) {
          int kg = half * 8 + kk;
          ac0 = __builtin_amdgcn_mfma_f32_16x16x32_bf16(Af(0, kg + 0), breg0[kk + 0], ac0, 0, 0, 0);
          ac1 = __builtin_amdgcn_mfma_f32_16x16x32_bf16(Af(0, kg + 1), breg0[kk + 1], ac1, 0, 0, 0);
          ac2 = __builtin_amdgcn_mfma_f32_16x16x32_bf16(Af(0, kg + 2), breg0[kk + 2], ac2, 0, 0, 0);
          ac3 = __builtin_amdgcn_mfma_f32_16x16x32_bf16(Af(0, kg + 3), breg0[kk + 3], ac3, 0, 0, 0);
        }
      }
      v4f acc;
#pragma unroll
      for (int r4 = 0; r4 < 4; ++r4) acc[r4] = (ac0[r4] + ac1[r4]) + (ac2[r4] + ac3[r4]);
#pragma unroll
      for (int r4 = 0; r4 < 4; ++r4) olds[w * 256 + (kq * 4 + r4) * 16 + col16] = acc[r4];
      bar_lds(); // S2

      if (tid < 256) {
        float gi = olds[tid] + olds[256 + tid];
        float gf = olds[512 + tid] + olds[768 + tid];
        float go = olds[1024 + tid] + olds[1280 + tid];
        float gg = olds[1536 + tid] + olds[1792 + tid];
        float i_s = sigm(gi), f_s = sigm(gf), o_s = sigm(go);
        float cg = tanhf(gg);
        float cy = f_s * c0 + i_s * cg;
        float hy = o_s * (tanhf(cy) + xi0);
        c0 = cy;
        u16 hyb = f2b(hy), cyb = f2b(cy);
        u32x2 pkt;
        pkt[0] = (u32)hyb | ((u32)cyb << 16);
        pkt[1] = (u32)(t + 1);
        void* pd = ring0 + ((size_t)((t + 1) & 3) * 4 + g) * 65536
                   + (size_t)(erow * 512 + hcol) * 8;
        asm volatile("global_store_dwordx2 %0, %1, off sc0 sc1"
                     :: "v"(pd), "v"(pkt) : "memory");
        if (t == T_STEPS - 1) {
          hn[bglob * 512 + hcol] = hy;
          cn[bglob * 512 + hcol] = cy;
        }
      }
    }

    // ========================= LAYER 1: position t-1 =========================
    if (doL1) {
      float xi1 = (tid < 256) ? b2f(alds[erow * 2056 + hcol]) : 0.0f;  // h0 tag t

      // ring1 check: counted drain (r2 loads are OLDER than this iter's lone
      // ring0 store on waves 0-3 -> vmcnt(1) drains r2 without waiting the
      // store ack; waves 4-7 / t==T_STEPS have no store -> vmcnt(0)).
      {
        const char* pb = ring1 + ((size_t)((t - 1) & 3) * 4 + g) * 65536 + (size_t)tid * 16;
        u32 exp = (u32)(t - 1), it = 0;
        if (doL0 && w < 4) asm volatile("s_waitcnt vmcnt(1)" ::: "memory");
        else               asm volatile("s_waitcnt vmcnt(0)" ::: "memory");
        __builtin_amdgcn_sched_barrier(0);
        for (;;) {
          bool ok = true;
#pragma unroll
          for (int i = 0; i < 8; ++i) ok = ok && (r2[i][1] == exp) && (r2[i][3] == exp);
          if (ok) break;
          if (++it > (1u << 11)) break;
          __builtin_amdgcn_s_sleep(1);
#pragma unroll
          for (int i = 0; i < 8; ++i)
            asm volatile("global_load_dwordx4 %0, %1, off sc0 sc1"
                         : "=v"(r2[i]) : "v"(pb + (size_t)i * 8192) : "memory");
          asm volatile("s_waitcnt vmcnt(0)" ::: "memory");
          __builtin_amdgcn_sched_barrier(0);
        }
        __builtin_amdgcn_sched_barrier(0);
#pragma unroll
        for (int i = 0; i < 8; ++i) {
          int p = tid + i * 512;
          int row = p >> 8, c2 = p & 255;
          u32 hw = (r2[i][0] & 0xffffu) | (r2[i][2] << 16);
          u32 cw = (r2[i][0] >> 16) | (r2[i][2] & 0xffff0000u);
          *reinterpret_cast<u32*>(alds + row * 2056 + 1024 + 2 * c2) = hw;
          *reinterpret_cast<u32*>(alds + row * 2056 + 1536 + 2 * c2) = cw;
        }
      }
      bar_lds(); // S3: ring1 staged; L0 done with olds

      v4f ac0, ac1, ac2, ac3;
#pragma unroll
      for (int r4 = 0; r4 < 4; ++r4) { ac0[r4] = bias1; ac1[r4] = 0.f; ac2[r4] = 0.f; ac3[r4] = 0.f; }
      if (isGate) {
#pragma unroll
        for (int kk = 0; kk < 16; kk += 4) {   // h1|c1 recurrent, this K-half
          int kg = half * 16 + kk;
          ac0 = __builtin_amdgcn_mfma_f32_16x16x32_bf16(Af(1024, kg + 0), breg1[kk + 0], ac0, 0, 0, 0);
          ac1 = __builtin_amdgcn_mfma_f32_16x16x32_bf16(Af(1024, kg + 1), breg1[kk + 1], ac1, 0, 0, 0);
          ac2 = __builtin_amdgcn_mfma_f32_16x16x32_bf16(Af(1024, kg + 2), breg1[kk + 2], ac2, 0, 0, 0);
          ac3 = __builtin_amdgcn_mfma_f32_16x16x32_bf16(Af(1024, kg + 3), breg1[kk + 3], ac3, 0, 0, 0);
        }
#pragma unroll
        for (int kx = 0; kx < 8; kx += 4) {    // x1 @ Wii1, this K-half (8 of 16)
          int kg = half * 8 + kx;
          ac0 = __builtin_amdgcn_mfma_f32_16x16x32_bf16(Af(0, kg + 0),
                  *reinterpret_cast<const v8bf*>(w1lds + ((w2 * 16 + kg + 0) * 64 + lane) * 8), ac0, 0, 0, 0);
          ac1 = __builtin_amdgcn_mfma_f32_16x16x32_bf16(Af(0, kg + 1),
                  *reinterpret_cast<const v8bf*>(w1lds + ((w2 * 16 + kg + 1) * 64 + lane) * 8), ac1, 0, 0, 0);
          ac2 = __builtin_amdgcn_mfma_f32_16x16x32_bf16(Af(0, kg + 2),
                  *reinterpret_cast<const v8bf*>(w1lds + ((w2 * 16 + kg + 2) * 64 + lane) * 8), ac2, 0, 0, 0);
          ac3 = __builtin_amdgcn_mfma_f32_16x16x32_bf16(Af(0, kg + 3),
                  *reinterpret_cast<const v8bf*>(w1lds + ((w2 * 16 + kg + 3) * 64 + lane) * 8), ac3, 0, 0, 0);
        }
      } else {
#pragma unroll
        for (int kk = 0; kk < 8; kk += 4) {    // cell: h1 only, this K-half
          int kg = half * 8 + kk;
          ac0 = __builtin_amdgcn_mfma_f32_16x16x32_bf16(Af(1024, kg + 0), breg1[kk + 0], ac0, 0, 0, 0);
          ac1 = __builtin_amdgcn_mfma_f32_16x16x32_bf16(Af(1024, kg + 1), breg1[kk + 1], ac1, 0, 0, 0);
          ac2 = __builtin_amdgcn_mfma_f32_16x16x32_bf16(Af(1024, kg + 2), breg1[kk + 2], ac2, 0, 0, 0);
          ac3 = __builtin_amdgcn_mfma_f32_16x16x32_bf16(Af(1024, kg + 3), breg1[kk + 3], ac3, 0, 0, 0);
        }
      }
      v4f acc;
#pragma unroll
      for (int r4 = 0; r4 < 4; ++r4) acc[r4] = (ac0[r4] + ac1[r4]) + (ac2[r4] + ac3[r4]);
#pragma unroll
      for (int r4 = 0; r4 < 4; ++r4) olds[w * 256 + (kq * 4 + r4) * 16 + col16] = acc[r4];
      bar_lds(); // S4

      if (tid < 256) {
        float gi = olds[tid] + olds[256 + tid];
        float gf = olds[512 + tid] + olds[768 + tid];
        float go = olds[1024 + tid] + olds[1280 + tid];
        float gg = olds[1536 + tid] + olds[1792 + tid];
        float i_s = sigm(gi), f_s = sigm(gf), o_s = sigm(go);
        float cg = tanhf(gg);
        float cy = f_s * c1 + i_s * cg;
        float hy = o_s * (tanhf(cy) + xi1);
        c1 = cy;
        u16 hyb = f2b(hy), cyb = f2b(cy);
        u32x2 pkt;
        pkt[0] = (u32)hyb | ((u32)cyb << 16);
        pkt[1] = (u32)t;
        void* pd = ring1 + ((size_t)(t & 3) * 4 + g) * 65536
                   + (size_t)(erow * 512 + hcol) * 8;
        asm volatile("global_store_dwordx2 %0, %1, off sc0 sc1"
                     :: "v"(pd), "v"(pkt) : "memory");
        outs[(size_t)((t - 1) * 64 + bglob) * 512 + hcol] = hy;
        if (t == T_STEPS) {
          hn[32768 + bglob * 512 + hcol] = hy;
          cn[32768 + bglob * 512 + hcol] = cy;
        }
      }
    }

    // ---- tail: prefetch next-iter seeds/xi (plain loads) + speculative ring0 ----
    if (t + 1 < T_STEPS) {
      if (isGate && half == 0) {
        const u16* xgp = xg + (size_t)((t + 1) * 64 + g * 16 + kq * 4) * G3 + colglob;
        pre_s0 = b2f(xgp[0]);
        pre_s1 = b2f(xgp[(size_t)G3]);
        pre_s2 = b2f(xgp[(size_t)2 * G3]);
        pre_s3 = b2f(xgp[(size_t)3 * G3]);
      }
      if (tid < 256) pre_xi = xin[(size_t)((t + 1) * 64 + bglob) * 512 + hcol];
    }
    if (t < T_STEPS) {
      const char* pb0 = ring0 + ((size_t)((t + 1) & 3) * 4 + g) * 65536 + (size_t)tid * 16;
#pragma unroll
      for (int i = 0; i < 8; ++i)
        asm volatile("global_load_dwordx4 %0, %1, off sc0 sc1"
                     : "=v"(rA[i]) : "v"(pb0 + (size_t)i * 8192) : "memory");
    }
    bar_lds(); // S5: LDS WAR fence; spec loads stay in flight across it
  }
}

// ---------------- launch ----------------

extern "C" void kernel_launch(void* const* d_in, const int* in_sizes, int n_in,
                              void* d_out, int out_size, void* d_ws, size_t ws_size,
                              hipStream_t stream) {
  const float* x   = (const float*)d_in[0];
  const float* Wii = (const float*)d_in[1];
  const float* Wic = (const float*)d_in[2];
  const float* Wih = (const float*)d_in[3];
  const float* bii = (const float*)d_in[4];
  const float* bic = (const float*)d_in[5];
  const float* bih = (const float*)d_in[6];
  const float* Whh = (const float*)d_in[7];
  const float* bhh = (const float*)d_in[8];
  float* out = (float*)d_out;
  char* ws = (char*)d_ws;

  u16* xbf     = (u16*)(ws + OFF_XBF);
  u16* xgb     = (u16*)(ws + OFF_XG);
  u16* wiib    = (u16*)(ws + OFF_WII);
  u16* wpack   = (u16*)(ws + OFF_WPACK);
  u16* wpk2    = (u16*)(ws + OFF_WPK2);
  float* biasf = (float*)(ws + OFF_BIASF);

  hipFuncSetAttribute(reinterpret_cast<const void*>(k_lstm),
                      hipFuncAttributeMaxDynamicSharedMemorySize, 123136);

  // prep
  k_cvt <<<2048, 256, 0, stream>>>(x, xbf, 8388608);
  k_cvt <<<768, 256, 0, stream>>>(Wii, wiib, 196608);          // layer-0 Wii only
  k_fold<<<12, 256, 0, stream>>>(bii, bic, bih, biasf, 3072);
  k_pack<<<1792, 256, 0, stream>>>(Wih, Wic, Whh, wpack);
  k_pack2<<<384, 256, 0, stream>>>(Wii, wpk2);
  k_gemm<<<dim3(512, 12), 256, 0, stream>>>(xbf, wiib, xgb);   // xg0 only

  // rings overlap head of xbf: clear AFTER k_gemm consumed it.
  hipMemsetAsync(ws + OFF_RING0, 0, 2097152, stream);

  float* hn = out + 33554432;
  float* cn = out + 33554432 + 65536;
  k_lstm<<<128, 512, 123136, stream>>>(
      xgb, wpack, wpk2, biasf, bhh, x, out, hn, cn,
      ws + OFF_RING0, ws + OFF_RING1);
}